// Round 23
// baseline (112.149 us; speedup 1.0000x reference)
//
#include <hip/hip_runtime.h>
#include <hip/hip_bf16.h>
#include <math.h>

constexpr int N = 16384, D = 256, C = 10000;
constexpr float S = 30.0f, MARGIN = 0.4f;
constexpr int BM = 128, BN = 80;             // C == 125*80 exactly: no padding
constexpr int YG = 5;                        // y-panels per block
constexpr int NX = N / BM;                   // 128 row tiles
constexpr int NY = C / BN;                   // 125 col tiles
constexpr int NYG = NY / YG;                 // 25 panel groups
constexpr int NWG = NX * NYG;                // 3200 = 8 * 16 * 25
constexpr float S_LOG2E = 43.2808512266689f; // S * log2(e) (baked into A fp8)

constexpr int PREPX_BLOCKS = N / 16;          // 1024 (16-row groups, fp8 frag pack)
constexpr int PREPW_BLOCKS = C / 16;          // 625  (16-col groups, fp8 frag pack)

using bf16 = __hip_bfloat16;
typedef __attribute__((ext_vector_type(4))) int   int4v;
typedef __attribute__((ext_vector_type(8))) int   int8v;
typedef __attribute__((ext_vector_type(4))) float f32x4;

#define DRAIN_DMA()                                        \
    do {                                                   \
        asm volatile("s_waitcnt vmcnt(0)" ::: "memory");   \
        __builtin_amdgcn_sched_barrier(0);                 \
    } while (0)

// pack 4 floats -> 4 fp8(e4m3) bytes in one dword
__device__ inline int pk4_fp8(float e0, float e1, float e2, float e3) {
    int lo = __builtin_amdgcn_cvt_pk_fp8_f32(e0, e1, 0, false);
    return  __builtin_amdgcn_cvt_pk_fp8_f32(e2, e3, lo, true);
}

// ---------------- fused prep ----------------
// K=128 fp8 fragment layout (R22-verified): frag (g16, kk) = 2048 B; lane l
// covers row g16*16+(l&15), k = kk*128 + (l>>4)*32 + j; identical bijection
// for A and B -> exact dot product regardless of within-lane k-order.
// A values pre-scaled by S*log2e (scale-invariant relative fp8 error), so
// the GEMM accumulator IS the exp2 argument. tgt stays exact f32.
__global__ __launch_bounds__(256) void prep(const float* __restrict__ x,
                                            const int* __restrict__ labels,
                                            const float* __restrict__ W,
                                            char* __restrict__ Af,
                                            float* __restrict__ tgt,
                                            char* __restrict__ Bf,
                                            float* __restrict__ out) {
    const int bid = blockIdx.x;
    if (bid == 0 && threadIdx.x == 0) out[0] = 0.0f;

    const int tl = threadIdx.x;
    const int r = tl >> 4, c = tl & 15;
    auto frag_off = [&](int g16) -> size_t {
        return ((size_t)g16 * 2 + (c >> 3)) * 2048 + (size_t)(c & 1) * 1024
             + (size_t)((((c >> 1) & 3) * 16 + r)) * 16;
    };

    if (bid < PREPX_BLOCKS) {
        const int rg = bid;
        const int row = rg * 16 + r;
        const float* xr = x + (size_t)row * D + c * 16;
        f32x4 v0 = *(const f32x4*)(xr + 0);
        f32x4 v1 = *(const f32x4*)(xr + 4);
        f32x4 v2 = *(const f32x4*)(xr + 8);
        f32x4 v3 = *(const f32x4*)(xr + 12);

        float ssq = v0.x*v0.x + v0.y*v0.y + v0.z*v0.z + v0.w*v0.w
                  + v1.x*v1.x + v1.y*v1.y + v1.z*v1.z + v1.w*v1.w
                  + v2.x*v2.x + v2.y*v2.y + v2.z*v2.z + v2.w*v2.w
                  + v3.x*v3.x + v3.y*v3.y + v3.z*v3.z + v3.w*v3.w;
        ssq += __shfl_xor(ssq, 1);
        ssq += __shfl_xor(ssq, 2);
        ssq += __shfl_xor(ssq, 4);
        ssq += __shfl_xor(ssq, 8);
        float rinv = rsqrtf(ssq);

        const int lab = labels[row];
        const float* wr = W + (size_t)lab * D + c * 16;
        f32x4 w0 = *(const f32x4*)(wr + 0);
        f32x4 w1 = *(const f32x4*)(wr + 4);
        f32x4 w2 = *(const f32x4*)(wr + 8);
        f32x4 w3 = *(const f32x4*)(wr + 12);
        float td = v0.x*w0.x + v0.y*w0.y + v0.z*w0.z + v0.w*w0.w
                 + v1.x*w1.x + v1.y*w1.y + v1.z*w1.z + v1.w*w1.w
                 + v2.x*w2.x + v2.y*w2.y + v2.z*w2.z + v2.w*w2.w
                 + v3.x*w3.x + v3.y*w3.y + v3.z*w3.z + v3.w*w3.w;
        td += __shfl_xor(td, 1);
        td += __shfl_xor(td, 2);
        td += __shfl_xor(td, 4);
        td += __shfl_xor(td, 8);
        if (c == 0) tgt[row] = td * rinv;   // exact f32 numerator path

        const float sc = rinv * S_LOG2E;    // fold S*log2e into A (scale-invariant err)
        int4v pk;
        pk.x = pk4_fp8(v0.x * sc, v0.y * sc, v0.z * sc, v0.w * sc);
        pk.y = pk4_fp8(v1.x * sc, v1.y * sc, v1.z * sc, v1.w * sc);
        pk.z = pk4_fp8(v2.x * sc, v2.y * sc, v2.z * sc, v2.w * sc);
        pk.w = pk4_fp8(v3.x * sc, v3.y * sc, v3.z * sc, v3.w * sc);
        *(int4v*)(Af + frag_off(rg)) = pk;
    } else {
        const int rg = bid - PREPX_BLOCKS;     // 16-col group 0..624
        const int row = rg * 16 + r;           // class index (< C always)
        const float* wr = W + (size_t)row * D + c * 16;
        f32x4 v0 = *(const f32x4*)(wr + 0);
        f32x4 v1 = *(const f32x4*)(wr + 4);
        f32x4 v2 = *(const f32x4*)(wr + 8);
        f32x4 v3 = *(const f32x4*)(wr + 12);
        int4v pk;
        pk.x = pk4_fp8(v0.x, v0.y, v0.z, v0.w);
        pk.y = pk4_fp8(v1.x, v1.y, v1.z, v1.w);
        pk.z = pk4_fp8(v2.x, v2.y, v2.z, v2.w);
        pk.w = pk4_fp8(v3.x, v3.y, v3.z, v3.w);
        *(int4v*)(Bf + frag_off(rg)) = pk;
    }
}

// ---------------- main GEMM (MX-fp8 K=128) + exp2 + per-tile row partials ----------------
// R22 base + y-loop: A fragments register-resident ONCE (32 VGPR), block
// sweeps YG=5 B panels with a double-buffered 20 KB LDS stage. Panel p+1's
// DMA is issued before panel p's compute+epilogue (~1000 cyc) -> the single
// per-panel barrier is covered. A L2 traffic /5, prologue latency /5,
// blocks 16000 -> 3200. LDS 2x20KB + 512B eps = 41 KB -> 3 blocks/CU.
__global__ __launch_bounds__(256) void gemm_exp(const char* __restrict__ Af,
                                                const char* __restrict__ Bf,
                                                bf16* __restrict__ partial) { // [NY][N] bf16
    __shared__ __align__(16) char Bs[2][BN * D];   // 2 x 20 KB, fragment order
    __shared__ float eps[BM];                      // 512 B epilogue scratch

    // ---- XCD-aware decode (bijective: NWG = 8 * 16 * 25) ----
    const int bid = blockIdx.x;
    const int xcd = bid & 7;
    const int idx = bid >> 3;          // 0..399
    const int xl  = idx & 15;          // x within XCD chunk (fast)
    const int yg  = idx >> 4;          // 0..24 (slow)
    const int tile_r = (xcd * 16 + xl) * BM;
    const int y0 = yg * YG;            // first panel

    const int t = threadIdx.x;
    const int lane = t & 63, w = t >> 6;   // wave w owns rows w*32..+32, all 80 cols

    // stage panel y0+p into buffer b (20 chunks of 1 KB; linear frag order)
    auto STAGE = [&](int p, int b) {
        #pragma unroll
        for (int q = 0; q < 5; ++q) {
            int cch = w * 5 + q;                  // chunk 0..19, wave-uniform
            const char* gb = Bf + (size_t)(y0 + p) * 10 * 2048 + (size_t)cch * 1024 + lane * 16;
            __builtin_amdgcn_global_load_lds(
                (const __attribute__((address_space(1))) void*)gb,
                (__attribute__((address_space(3))) void*)(&Bs[b][0] + cch * 1024),
                16, 0, 0);
        }
    };

    // ---- prologue: stage panel 0; A fragments -> registers (once) ----
    STAGE(0, 0);
    int8v a[2][2];   // [kk][m]
    #pragma unroll
    for (int kk = 0; kk < 2; ++kk)
        #pragma unroll
        for (int m = 0; m < 2; ++m) {
            const char* base = Af + ((size_t)((tile_r >> 4) + w * 2 + m) * 2 + kk) * 2048;
            int4v lo = *(const int4v*)(base + lane * 16);
            int4v hi = *(const int4v*)(base + 1024 + lane * 16);
            a[kk][m] = int8v{lo.x, lo.y, lo.z, lo.w, hi.x, hi.y, hi.z, hi.w};
        }
    DRAIN_DMA();
    __syncthreads();   // panel 0 visible

    // ---- y-loop: 5 panels, fully unrolled (static buffer indices) ----
    #pragma unroll
    for (int p = 0; p < YG; ++p) {
        const int cur = p & 1;
        if (p + 1 < YG) STAGE(p + 1, cur ^ 1);   // in flight during compute+epilogue

        f32x4 acc[2][5] = {};
        #pragma unroll
        for (int kk = 0; kk < 2; ++kk) {
            int8v b[5];
            #pragma unroll
            for (int n = 0; n < 5; ++n) {
                const char* base = &Bs[cur][0] + (n * 2 + kk) * 2048;
                int4v lo = *(const int4v*)(base + lane * 16);
                int4v hi = *(const int4v*)(base + 1024 + lane * 16);
                b[n] = int8v{lo.x, lo.y, lo.z, lo.w, hi.x, hi.y, hi.z, hi.w};
            }
            #pragma unroll
            for (int m = 0; m < 2; ++m)
                #pragma unroll
                for (int n = 0; n < 5; ++n)
                    acc[m][n] = __builtin_amdgcn_mfma_scale_f32_16x16x128_f8f6f4(
                        a[kk][m], b[n], acc[m][n],
                        0 /*cbsz: fp8*/, 0 /*blgp: fp8*/,
                        0, 0x7F7F7F7F,   // scale A = 1.0
                        0, 0x7F7F7F7F);  // scale B = 1.0
        }

        // epilogue: exp2(acc) (S*log2e baked into A), row sums -> eps
        #pragma unroll
        for (int m = 0; m < 2; ++m) {
            float rs[4] = {0.f, 0.f, 0.f, 0.f};
            #pragma unroll
            for (int n = 0; n < 5; ++n) {
                #pragma unroll
                for (int r = 0; r < 4; ++r)
                    rs[r] += __builtin_amdgcn_exp2f(acc[m][n][r]);
            }
            #pragma unroll
            for (int r = 0; r < 4; ++r) {
                float v = rs[r];
                v += __shfl_xor(v, 1);
                v += __shfl_xor(v, 2);
                v += __shfl_xor(v, 4);
                v += __shfl_xor(v, 8);
                if ((lane & 15) == 0)
                    eps[w * 32 + m * 16 + (lane >> 4) * 4 + r] = v;
            }
        }
        DRAIN_DMA();        // panel p+1 DMA landed (covered by compute+epilogue)
        __syncthreads();    // eps complete; all waves done reading Bs[cur]
        if (t < BM)
            partial[(size_t)(y0 + p) * N + tile_r + t] = __float2bfloat16(eps[t]);
        // next iteration's STAGE targets Bs[cur] — safe: all reads done (barrier)
    }
}

// ---------------- loss: reduce partials (5-way ILP) + per-row loss + atomic ----------------
__global__ __launch_bounds__(256) void loss_part(const float* __restrict__ tgt,
                                                 const bf16* __restrict__ partial,
                                                 float* __restrict__ out) {
    int i = blockIdx.x * 256 + threadIdx.x;   // row
    float s0 = 0.f, s1 = 0.f, s2 = 0.f, s3 = 0.f, s4 = 0.f;
    #pragma unroll 1
    for (int y = 0; y < NY; y += 5) {
        s0 += __bfloat162float(partial[(size_t)(y + 0) * N + i]);
        s1 += __bfloat162float(partial[(size_t)(y + 1) * N + i]);
        s2 += __bfloat162float(partial[(size_t)(y + 2) * N + i]);
        s3 += __bfloat162float(partial[(size_t)(y + 3) * N + i]);
        s4 += __bfloat162float(partial[(size_t)(y + 4) * N + i]);
    }
    float sum = ((s0 + s1) + (s2 + s3)) + s4;

    float tg = tgt[i];
    float num = S * (tg - MARGIN);
    float den = __expf(num) + sum - __expf(S * tg);
    float L = num - logf(den);

    float v = L;
    #pragma unroll
    for (int off = 1; off < 64; off <<= 1) v += __shfl_xor(v, off);
    __shared__ float s4m[4];
    int lane = threadIdx.x & 63, w = threadIdx.x >> 6;
    if (lane == 0) s4m[w] = v;
    __syncthreads();
    if (threadIdx.x == 0) {
        float bsum = s4m[0] + s4m[1] + s4m[2] + s4m[3];
        atomicAdd(out, -bsum / (float)N);
    }
}

// ---------------- launch ----------------
extern "C" void kernel_launch(void* const* d_in, const int* in_sizes, int n_in,
                              void* d_out, int out_size, void* d_ws, size_t ws_size,
                              hipStream_t stream) {
    const float* x = (const float*)d_in[0];
    const int* labels = (const int*)d_in[1];
    const float* W = (const float*)d_in[2];

    char* ws = (char*)d_ws;
    char* Af       = ws;                             // N*D fp8 (frag order)  = 4,194,304
    char* Bf       = ws + 4194304;                   // C*D fp8 (frag order)  = 2,560,000
    float* tgt     = (float*)(ws + 6754304);         // N*4                   =    65,536
    bf16* partial  = (bf16*)(ws + 6819840);          // NY*N*2                = 4,096,000
    float* out = (float*)d_out;                      // total 10,915,840

    prep<<<PREPX_BLOCKS + PREPW_BLOCKS, 256, 0, stream>>>(x, labels, W, Af, tgt, Bf, out);
    gemm_exp<<<NWG, 256, 0, stream>>>(Af, Bf, partial);
    loss_part<<<N / 256, 256, 0, stream>>>(tgt, partial, out);
}

// Round 24
// 92.761 us; speedup vs baseline: 1.2090x; 1.2090x over previous
//
#include <hip/hip_runtime.h>
#include <hip/hip_bf16.h>
#include <math.h>

constexpr int N = 16384, D = 256, C = 10000;
constexpr float S = 30.0f, MARGIN = 0.4f;
constexpr int BM = 128, BN = 80;             // C == 125*80 exactly: no padding
constexpr int NX = N / BM;                   // 128 row tiles
constexpr int NY = C / BN;                   // 125 col tiles
constexpr int NWG = NX * NY;                 // 16000 = 8 * 16 * 125
constexpr float S_LOG2E = 43.2808512266689f; // S * log2(e)  (applied in epilogue)

constexpr int PREPX_BLOCKS = N / 16;          // 1024 (16-row groups, fp8 frag pack)
constexpr int PREPW_BLOCKS = C / 16;          // 625  (16-col groups, fp8 frag pack)

using bf16 = __hip_bfloat16;
typedef __attribute__((ext_vector_type(4))) int   int4v;
typedef __attribute__((ext_vector_type(8))) int   int8v;
typedef __attribute__((ext_vector_type(4))) float f32x4;

#define DRAIN_DMA()                                        \
    do {                                                   \
        asm volatile("s_waitcnt vmcnt(0)" ::: "memory");   \
        __builtin_amdgcn_sched_barrier(0);                 \
    } while (0)

// pack 4 floats -> 4 fp8(e4m3) bytes in one dword (little-endian order e0..e3)
__device__ inline int pk4_fp8(float e0, float e1, float e2, float e3) {
    int lo = __builtin_amdgcn_cvt_pk_fp8_f32(e0, e1, 0, false);   // bytes 0,1
    return  __builtin_amdgcn_cvt_pk_fp8_f32(e2, e3, lo, true);    // bytes 2,3
}

// ---------------- fused prep ----------------
// Both operands packed into the K=128 fp8 fragment layout (R22-verified):
//   frag (g16, kk) = 2048 B; lane l covers row g16*16+(l&15),
//   k = kk*128 + (l>>4)*32 + j, j=0..31; byte addr within frag =
//   (j>>4)*1024 + l*16 + (j&15). A and B use the IDENTICAL bijection ->
//   exact dot product regardless of within-lane k-order; uniform scale
//   0x7F (=1.0) makes scale-block indexing immaterial.
// x: normalize (f32), convert xn to e4m3. tgt exact f32.
// W: convert to e4m3 (no padding: C = 625*16).
__global__ __launch_bounds__(256) void prep(const float* __restrict__ x,
                                            const int* __restrict__ labels,
                                            const float* __restrict__ W,
                                            char* __restrict__ Af,
                                            float* __restrict__ tgt,
                                            char* __restrict__ Bf,
                                            float* __restrict__ out) {
    const int bid = blockIdx.x;
    if (bid == 0 && threadIdx.x == 0) out[0] = 0.0f;

    const int tl = threadIdx.x;
    const int r = tl >> 4, c = tl & 15;
    auto frag_off = [&](int g16) -> size_t {
        return ((size_t)g16 * 2 + (c >> 3)) * 2048 + (size_t)(c & 1) * 1024
             + (size_t)((((c >> 1) & 3) * 16 + r)) * 16;
    };

    if (bid < PREPX_BLOCKS) {
        const int rg = bid;
        const int row = rg * 16 + r;
        const float* xr = x + (size_t)row * D + c * 16;
        f32x4 v0 = *(const f32x4*)(xr + 0);
        f32x4 v1 = *(const f32x4*)(xr + 4);
        f32x4 v2 = *(const f32x4*)(xr + 8);
        f32x4 v3 = *(const f32x4*)(xr + 12);

        float ssq = v0.x*v0.x + v0.y*v0.y + v0.z*v0.z + v0.w*v0.w
                  + v1.x*v1.x + v1.y*v1.y + v1.z*v1.z + v1.w*v1.w
                  + v2.x*v2.x + v2.y*v2.y + v2.z*v2.z + v2.w*v2.w
                  + v3.x*v3.x + v3.y*v3.y + v3.z*v3.z + v3.w*v3.w;
        ssq += __shfl_xor(ssq, 1);
        ssq += __shfl_xor(ssq, 2);
        ssq += __shfl_xor(ssq, 4);
        ssq += __shfl_xor(ssq, 8);
        float rinv = rsqrtf(ssq);

        const int lab = labels[row];
        const float* wr = W + (size_t)lab * D + c * 16;
        f32x4 w0 = *(const f32x4*)(wr + 0);
        f32x4 w1 = *(const f32x4*)(wr + 4);
        f32x4 w2 = *(const f32x4*)(wr + 8);
        f32x4 w3 = *(const f32x4*)(wr + 12);
        float td = v0.x*w0.x + v0.y*w0.y + v0.z*w0.z + v0.w*w0.w
                 + v1.x*w1.x + v1.y*w1.y + v1.z*w1.z + v1.w*w1.w
                 + v2.x*w2.x + v2.y*w2.y + v2.z*w2.z + v2.w*w2.w
                 + v3.x*w3.x + v3.y*w3.y + v3.z*w3.z + v3.w*w3.w;
        td += __shfl_xor(td, 1);
        td += __shfl_xor(td, 2);
        td += __shfl_xor(td, 4);
        td += __shfl_xor(td, 8);
        if (c == 0) tgt[row] = td * rinv;   // exact f32 numerator path

        int4v pk;
        pk.x = pk4_fp8(v0.x * rinv, v0.y * rinv, v0.z * rinv, v0.w * rinv);
        pk.y = pk4_fp8(v1.x * rinv, v1.y * rinv, v1.z * rinv, v1.w * rinv);
        pk.z = pk4_fp8(v2.x * rinv, v2.y * rinv, v2.z * rinv, v2.w * rinv);
        pk.w = pk4_fp8(v3.x * rinv, v3.y * rinv, v3.z * rinv, v3.w * rinv);
        *(int4v*)(Af + frag_off(rg)) = pk;
    } else {
        const int rg = bid - PREPX_BLOCKS;     // 16-col group 0..624
        const int row = rg * 16 + r;           // class index (< C always)
        const float* wr = W + (size_t)row * D + c * 16;
        f32x4 v0 = *(const f32x4*)(wr + 0);
        f32x4 v1 = *(const f32x4*)(wr + 4);
        f32x4 v2 = *(const f32x4*)(wr + 8);
        f32x4 v3 = *(const f32x4*)(wr + 12);
        int4v pk;
        pk.x = pk4_fp8(v0.x, v0.y, v0.z, v0.w);
        pk.y = pk4_fp8(v1.x, v1.y, v1.z, v1.w);
        pk.z = pk4_fp8(v2.x, v2.y, v2.z, v2.w);
        pk.w = pk4_fp8(v3.x, v3.y, v3.z, v3.w);
        *(int4v*)(Bf + frag_off(rg)) = pk;
    }
}

// ---------------- main GEMM (MX-fp8 K=128) + exp2 + per-tile row partials ----------------
// R22 verified optimum (gemm 80.5 us, total 92.2): BM=128 x BN=80, 4 waves,
// per-wave 32x80 (acc[2][5] = 40 VGPR). B panel (10 frags, 20 KB) staged
// linearly into LDS; A fragments fully register-resident before the single
// barrier. Uniform scale 0x7F7F7F7F (=1.0). SOLE change vs R22: s_setprio(1)
// around the MFMA cluster (pure SALU hint, zero allocation impact; blocks
// here are independent/non-lockstep = the T5 regime). R23's y-loop regressed
// (LDS 41KB -> 3 blocks/CU, serialized panels) — do not re-attempt.
__global__ __launch_bounds__(256) void gemm_exp(const char* __restrict__ Af,
                                                const char* __restrict__ Bf,
                                                bf16* __restrict__ partial) { // [NY][N] bf16
    __shared__ __align__(16) char Bs[BN * D];   // 20 KB, fragment order

    // ---- XCD-aware decode (bijective: NWG = 8 * 16 * 125) ----
    const int bid = blockIdx.x;
    const int xcd = bid & 7;
    const int idx = bid >> 3;          // 0..1999
    const int xl  = idx & 15;          // x within XCD chunk (fast)
    const int y   = idx >> 4;          // 0..124 (slow)
    const int tile_r = (xcd * 16 + xl) * BM;

    const int t = threadIdx.x;
    const int lane = t & 63, w = t >> 6;   // wave w owns rows w*32..+32, all 80 cols

    // ---- prologue: stage B panel = linear 20 KB copy (frag order preserved) ----
    #pragma unroll
    for (int q = 0; q < 5; ++q) {
        int cch = w * 5 + q;                      // chunk 0..19, wave-uniform
        const char* gb = Bf + (size_t)y * 10 * 2048 + (size_t)cch * 1024 + lane * 16;
        __builtin_amdgcn_global_load_lds(
            (const __attribute__((address_space(1))) void*)gb,
            (__attribute__((address_space(3))) void*)(Bs + cch * 1024),
            16, 0, 0);
    }

    // ---- A fragments: fully register-resident (2 m x 2 kk x 32 B/lane) ----
    int8v a[2][2];   // [kk][m]
    #pragma unroll
    for (int kk = 0; kk < 2; ++kk)
        #pragma unroll
        for (int m = 0; m < 2; ++m) {
            const char* base = Af + ((size_t)((tile_r >> 4) + w * 2 + m) * 2 + kk) * 2048;
            int4v lo = *(const int4v*)(base + lane * 16);
            int4v hi = *(const int4v*)(base + 1024 + lane * 16);
            a[kk][m] = int8v{lo.x, lo.y, lo.z, lo.w, hi.x, hi.y, hi.z, hi.w};
        }

    f32x4 acc[2][5] = {};

    DRAIN_DMA();
    __syncthreads();   // B panel fully visible; the ONLY K-path barrier

    #pragma unroll
    for (int kk = 0; kk < 2; ++kk) {
        int8v b[5];
        #pragma unroll
        for (int n = 0; n < 5; ++n) {
            const char* base = Bs + (n * 2 + kk) * 2048;
            int4v lo = *(const int4v*)(base + lane * 16);
            int4v hi = *(const int4v*)(base + 1024 + lane * 16);
            b[n] = int8v{lo.x, lo.y, lo.z, lo.w, hi.x, hi.y, hi.z, hi.w};
        }
        __builtin_amdgcn_s_setprio(1);
        #pragma unroll
        for (int m = 0; m < 2; ++m)
            #pragma unroll
            for (int n = 0; n < 5; ++n)
                acc[m][n] = __builtin_amdgcn_mfma_scale_f32_16x16x128_f8f6f4(
                    a[kk][m], b[n], acc[m][n],
                    0 /*cbsz: fp8*/, 0 /*blgp: fp8*/,
                    0, 0x7F7F7F7F,   // scale A = 1.0 (every byte)
                    0, 0x7F7F7F7F);  // scale B = 1.0
        __builtin_amdgcn_s_setprio(0);
    }

    __syncthreads();   // K-loop reads of Bs done; reuse as epilogue scratch
    float* eps = (float*)Bs;   // 128 floats

    // ---- epilogue: exp2(S_LOG2E * acc), row sums (rows unique per wave) ----
    #pragma unroll
    for (int m = 0; m < 2; ++m) {
        float rs[4] = {0.f, 0.f, 0.f, 0.f};
        #pragma unroll
        for (int n = 0; n < 5; ++n) {
            #pragma unroll
            for (int r = 0; r < 4; ++r)
                rs[r] += __builtin_amdgcn_exp2f(acc[m][n][r] * S_LOG2E);
        }
        #pragma unroll
        for (int r = 0; r < 4; ++r) {
            float v = rs[r];
            v += __shfl_xor(v, 1);
            v += __shfl_xor(v, 2);
            v += __shfl_xor(v, 4);
            v += __shfl_xor(v, 8);
            if ((lane & 15) == 0)
                eps[w * 32 + m * 16 + (lane >> 4) * 4 + r] = v;
        }
    }
    __syncthreads();
    if (t < BM)
        partial[(size_t)y * N + tile_r + t] = __float2bfloat16(eps[t]);  // coalesced
}

// ---------------- loss: reduce partials (5-way ILP) + per-row loss + atomic ----------------
__global__ __launch_bounds__(256) void loss_part(const float* __restrict__ tgt,
                                                 const bf16* __restrict__ partial,
                                                 float* __restrict__ out) {
    int i = blockIdx.x * 256 + threadIdx.x;   // row
    float s0 = 0.f, s1 = 0.f, s2 = 0.f, s3 = 0.f, s4 = 0.f;
    #pragma unroll 1
    for (int y = 0; y < NY; y += 5) {
        s0 += __bfloat162float(partial[(size_t)(y + 0) * N + i]);
        s1 += __bfloat162float(partial[(size_t)(y + 1) * N + i]);
        s2 += __bfloat162float(partial[(size_t)(y + 2) * N + i]);
        s3 += __bfloat162float(partial[(size_t)(y + 3) * N + i]);
        s4 += __bfloat162float(partial[(size_t)(y + 4) * N + i]);
    }
    float sum = ((s0 + s1) + (s2 + s3)) + s4;

    float tg = tgt[i];
    float num = S * (tg - MARGIN);
    float den = __expf(num) + sum - __expf(S * tg);
    float L = num - logf(den);

    float v = L;
    #pragma unroll
    for (int off = 1; off < 64; off <<= 1) v += __shfl_xor(v, off);
    __shared__ float s4m[4];
    int lane = threadIdx.x & 63, w = threadIdx.x >> 6;
    if (lane == 0) s4m[w] = v;
    __syncthreads();
    if (threadIdx.x == 0) {
        float bsum = s4m[0] + s4m[1] + s4m[2] + s4m[3];
        atomicAdd(out, -bsum / (float)N);
    }
}

// ---------------- launch ----------------
extern "C" void kernel_launch(void* const* d_in, const int* in_sizes, int n_in,
                              void* d_out, int out_size, void* d_ws, size_t ws_size,
                              hipStream_t stream) {
    const float* x = (const float*)d_in[0];
    const int* labels = (const int*)d_in[1];
    const float* W = (const float*)d_in[2];

    char* ws = (char*)d_ws;
    char* Af       = ws;                             // N*D fp8 (frag order)  = 4,194,304
    char* Bf       = ws + 4194304;                   // C*D fp8 (frag order)  = 2,560,000
    float* tgt     = (float*)(ws + 6754304);         // N*4                   =    65,536
    bf16* partial  = (bf16*)(ws + 6819840);          // NY*N*2                = 4,096,000
    float* out = (float*)d_out;                      // total 10,915,840

    prep<<<PREPX_BLOCKS + PREPW_BLOCKS, 256, 0, stream>>>(x, labels, W, Af, tgt, Bf, out);
    gemm_exp<<<NWG, 256, 0, stream>>>(Af, Bf, partial);
    loss_part<<<N / 256, 256, 0, stream>>>(tgt, partial, out);
}